// Round 1
// baseline (170.628 us; speedup 1.0000x reference)
//
#include <hip/hip_runtime.h>
#include <hip/hip_bf16.h>
#include <stdint.h>

// Problem constants
#define NC 512     // NUM_CLASSES
#define FD 1024    // FEAT_DIM
#define NB 64      // BATCH
#define SMOOTH_ 0.01f

typedef __bf16 bf16x8 __attribute__((ext_vector_type(8)));
typedef float f32x4 __attribute__((ext_vector_type(4)));

__device__ __forceinline__ unsigned short f2bf(float f) {
    __hip_bfloat16 h = __float2bfloat16(f);
    return __builtin_bit_cast(unsigned short, h);
}

__device__ __forceinline__ void gload_lds16(const void* g, void* l) {
    __builtin_amdgcn_global_load_lds(
        (const __attribute__((address_space(1))) void*)(uintptr_t)g,
        (__attribute__((address_space(3))) void*)(uint32_t)(uintptr_t)l,
        16, 0, 0);
}

// ---------------------------------------------------------------------------
// K1: build edge weights ew[512][512], store as bf16 bits.
// One block (256 thr) per output row i.
// ---------------------------------------------------------------------------
__global__ __launch_bounds__(256) void build_ew(
    const float* __restrict__ co, const float* __restrict__ counts,
    const float* __restrict__ emb, unsigned short* __restrict__ ew) {
    __shared__ float s_counts[NC];
    __shared__ float s_nemb[NC * 4];
    __shared__ float s_redA[4], s_redM[4], s_redS[4];
    const int i = blockIdx.x;
    const int t = threadIdx.x;
    const int lane = t & 63, wv = t >> 6;

    float c0 = counts[t], c1 = counts[t + 256];
    s_counts[t] = c0;
    s_counts[t + 256] = c1;
    for (int r = t; r < NC; r += 256) {
        float e0 = emb[r * 4 + 0], e1 = emb[r * 4 + 1];
        float e2 = emb[r * 4 + 2], e3 = emb[r * 4 + 3];
        float inv = 1.0f / sqrtf(e0 * e0 + e1 * e1 + e2 * e2 + e3 * e3);
        s_nemb[r * 4 + 0] = e0 * inv;
        s_nemb[r * 4 + 1] = e1 * inv;
        s_nemb[r * 4 + 2] = e2 * inv;
        s_nemb[r * 4 + 3] = e3 * inv;
    }
    // mean(counts)
    float p = c0 + c1;
#pragma unroll
    for (int o = 32; o; o >>= 1) p += __shfl_down(p, o);
    if (lane == 0) s_redA[wv] = p;
    __syncthreads();
    const float avg = (s_redA[0] + s_redA[1] + s_redA[2] + s_redA[3]) * (1.0f / 512.0f);

    const float ci = s_counts[i];
    const float ni0 = s_nemb[i * 4 + 0], ni1 = s_nemb[i * 4 + 1];
    const float ni2 = s_nemb[i * 4 + 2], ni3 = s_nemb[i * 4 + 3];

    float v[2];
#pragma unroll
    for (int u = 0; u < 2; ++u) {
        const int j = t + u * 256;
        const float c = co[i * NC + j];
        const float cj = s_counts[j];
        const float nco = (c + SMOOTH_) / sqrtf((ci + SMOOTH_) * (cj + SMOOTH_));
        const float sim = ni0 * s_nemb[j * 4 + 0] + ni1 * s_nemb[j * 4 + 1] +
                          ni2 * s_nemb[j * 4 + 2] + ni3 * s_nemb[j * 4 + 3];
        const float aff = sim / (1.0f + expf(-(sim - 0.5f) * 10.0f));
        const float mn = fminf(ci, cj), mx = fmaxf(ci, cj);
        const float bal = (mn > SMOOTH_ && mx > SMOOTH_)
                              ? log1pf(mx / avg) * (mn / mx)
                              : SMOOTH_;
        const float conf = 2.0f / (1.0f + expf(-c * 0.2f)) - 1.0f;
        const float e = (j == i) ? 0.0f : nco * aff * bal * conf;
        v[u] = e * 5.0f;
    }
    // row max
    float m = fmaxf(v[0], v[1]);
#pragma unroll
    for (int o = 32; o; o >>= 1) m = fmaxf(m, __shfl_down(m, o));
    if (lane == 0) s_redM[wv] = m;
    __syncthreads();
    const float rowmax = fmaxf(fmaxf(s_redM[0], s_redM[1]), fmaxf(s_redM[2], s_redM[3]));
    // exp + sum
    const float e0 = expf(v[0] - rowmax), e1 = expf(v[1] - rowmax);
    float s = e0 + e1;
#pragma unroll
    for (int o = 32; o; o >>= 1) s += __shfl_down(s, o);
    if (lane == 0) s_redS[wv] = s;
    __syncthreads();
    const float scale = 0.9f / (s_redS[0] + s_redS[1] + s_redS[2] + s_redS[3]);
    const float w0 = e0 * scale + ((t == i) ? 0.1f : 0.0f);
    const float w1 = e1 * scale + ((t + 256 == i) ? 0.1f : 0.0f);
    ew[i * NC + t] = f2bf(w0);
    ew[i * NC + t + 256] = f2bf(w1);
}

// ---------------------------------------------------------------------------
// K2: cast x[b,j,d] (f32) -> xT[b,d,j] (bf16 bits). 64x64 LDS tile transpose.
// grid (D/64=16, C/64=8, B=64), 256 threads.
// ---------------------------------------------------------------------------
__global__ __launch_bounds__(256) void cast_transpose(
    const float* __restrict__ x, unsigned short* __restrict__ xT) {
    __shared__ unsigned short sm[64][65];
    const int b = blockIdx.z;
    const int d0 = blockIdx.x * 64, j0 = blockIdx.y * 64;
    const int t = threadIdx.x;
    {
        const int jr = t >> 4, dc = (t & 15) * 4;
        const float* src = x + ((size_t)(b * NC + j0 + jr)) * FD + d0 + dc;
#pragma unroll
        for (int p = 0; p < 4; ++p) {
            float4 v = *reinterpret_cast<const float4*>(src + (size_t)p * 16 * FD);
            sm[jr + p * 16][dc + 0] = f2bf(v.x);
            sm[jr + p * 16][dc + 1] = f2bf(v.y);
            sm[jr + p * 16][dc + 2] = f2bf(v.z);
            sm[jr + p * 16][dc + 3] = f2bf(v.w);
        }
    }
    __syncthreads();
    {
        const int dl = t >> 4, jc = (t & 15) * 4;
        unsigned short* dst = xT + ((size_t)(b * FD + d0 + dl)) * NC + j0 + jc;
#pragma unroll
        for (int p = 0; p < 4; ++p) {
            const int d = dl + p * 16;
            ushort4 v;
            v.x = sm[jc + 0][d];
            v.y = sm[jc + 1][d];
            v.z = sm[jc + 2][d];
            v.w = sm[jc + 3][d];
            *reinterpret_cast<ushort4*>(dst + (size_t)p * 16 * NC) = v;
        }
    }
}

// ---------------------------------------------------------------------------
// K3: x_t[b,i,d] = sum_j ew[i,j] * x[b,j,d], written to d_out (f32).
// m97-style: 128x128 tile, BK=32, global_load_lds(16B), 4 waves, 4x4 frags
// of mfma_f32_16x16x32_bf16 per wave. grid (N/128=8, M/128=4, B=64).
// ---------------------------------------------------------------------------
__global__ __launch_bounds__(256) void gemm_xt(
    const unsigned short* __restrict__ ew, const unsigned short* __restrict__ xT,
    float* __restrict__ out) {
    __shared__ __align__(16) unsigned short smA[128 * 32];  // ew tile [128 i][32 j]
    __shared__ __align__(16) unsigned short smB[128 * 32];  // xT tile [128 d][32 j]
    const int t = threadIdx.x;
    const int lane = t & 63, wv = t >> 6;
    const int wr = wv >> 1, wc = wv & 1;  // wave sub-tile (64x64)
    const int b = blockIdx.z;
    const int i0 = blockIdx.y * 128, d0 = blockIdx.x * 128;

    const unsigned short* gA = ew + (size_t)(i0 + (t >> 2)) * NC + (t & 3) * 8;
    const unsigned short* gB =
        xT + ((size_t)b * FD + d0 + (t >> 2)) * NC + (t & 3) * 8;
    unsigned short* lA = smA + t * 8;  // byte offset t*16
    unsigned short* lB = smB + t * 8;

    f32x4 acc[4][4];
#pragma unroll
    for (int mi = 0; mi < 4; ++mi)
#pragma unroll
        for (int ni = 0; ni < 4; ++ni) acc[mi][ni] = (f32x4){0.f, 0.f, 0.f, 0.f};

    const int lr = lane & 15;
    const int kidx = lane >> 4;  // 0..3 -> k sub-block of 8

    for (int kt = 0; kt < NC / 32; ++kt) {
        const int k0 = kt * 32;
        gload_lds16(gA + k0, lA);
        gload_lds16(gA + (size_t)64 * NC + k0, lA + 64 * 32);
        gload_lds16(gB + k0, lB);
        gload_lds16(gB + (size_t)64 * NC + k0, lB + 64 * 32);
        __syncthreads();

        const bf16x8* A8 = reinterpret_cast<const bf16x8*>(smA);
        const bf16x8* B8 = reinterpret_cast<const bf16x8*>(smB);
        bf16x8 aF[4], bF[4];
#pragma unroll
        for (int mi = 0; mi < 4; ++mi)
            aF[mi] = A8[(wr * 64 + mi * 16 + lr) * 4 + kidx];
#pragma unroll
        for (int ni = 0; ni < 4; ++ni)
            bF[ni] = B8[(wc * 64 + ni * 16 + lr) * 4 + kidx];
#pragma unroll
        for (int mi = 0; mi < 4; ++mi)
#pragma unroll
            for (int ni = 0; ni < 4; ++ni)
                acc[mi][ni] = __builtin_amdgcn_mfma_f32_16x16x32_bf16(
                    aF[mi], bF[ni], acc[mi][ni], 0, 0, 0);
        __syncthreads();
    }

    // C/D layout: col = lane&15, row = (lane>>4)*4 + reg
    float* o = out + ((size_t)(b * NC + i0 + wr * 64)) * FD + d0 + wc * 64;
    const int cc = lane & 15;
    const int r0 = (lane >> 4) * 4;
#pragma unroll
    for (int mi = 0; mi < 4; ++mi)
#pragma unroll
        for (int ni = 0; ni < 4; ++ni)
#pragma unroll
            for (int r = 0; r < 4; ++r)
                o[(size_t)(mi * 16 + r0 + r) * FD + ni * 16 + cc] = acc[mi][ni][r];
}

// ---------------------------------------------------------------------------
// K4: in-place gate: out = x*(1-g) + x_t*g, g = sigmoid(dot(x,x_t)/32).
// One block (256 thr) per (b,i) row of 1024.
// ---------------------------------------------------------------------------
__global__ __launch_bounds__(256) void gate_out(
    const float* __restrict__ x, float* __restrict__ out) {
    __shared__ float s[4];
    const int row = blockIdx.x;
    const int t = threadIdx.x;
    const size_t base = (size_t)row * FD + t * 4;
    const float4 xv = *reinterpret_cast<const float4*>(x + base);
    const float4 tv = *reinterpret_cast<const float4*>(out + base);
    float p = xv.x * tv.x + xv.y * tv.y + xv.z * tv.z + xv.w * tv.w;
#pragma unroll
    for (int o = 32; o; o >>= 1) p += __shfl_down(p, o);
    if ((t & 63) == 0) s[t >> 6] = p;
    __syncthreads();
    const float dot = s[0] + s[1] + s[2] + s[3];
    const float g = 1.0f / (1.0f + expf(-dot * 0.03125f));
    float4 ov;
    ov.x = xv.x * (1.0f - g) + tv.x * g;
    ov.y = xv.y * (1.0f - g) + tv.y * g;
    ov.z = xv.z * (1.0f - g) + tv.z * g;
    ov.w = xv.w * (1.0f - g) + tv.w * g;
    *reinterpret_cast<float4*>(out + base) = ov;
}

extern "C" void kernel_launch(void* const* d_in, const int* in_sizes, int n_in,
                              void* d_out, int out_size, void* d_ws, size_t ws_size,
                              hipStream_t stream) {
    const float* x = (const float*)d_in[0];
    const float* co = (const float*)d_in[1];
    const float* counts = (const float*)d_in[2];
    const float* emb = (const float*)d_in[3];
    float* out = (float*)d_out;

    unsigned short* ew = (unsigned short*)d_ws;                          // 512 KB
    unsigned short* xT = (unsigned short*)((char*)d_ws + (1u << 20));    // 64 MiB

    build_ew<<<NC, 256, 0, stream>>>(co, counts, emb, ew);
    cast_transpose<<<dim3(FD / 64, NC / 64, NB), 256, 0, stream>>>(x, xT);
    gemm_xt<<<dim3(FD / 128, NC / 128, NB), 256, 0, stream>>>(ew, xT, out);
    gate_out<<<NB * NC, 256, 0, stream>>>(x, out);
}